// Round 4
// baseline (1296.722 us; speedup 1.0000x reference)
//
#include <hip/hip_runtime.h>

typedef _Float16 f16x8 __attribute__((ext_vector_type(8)));
typedef float f32x4 __attribute__((ext_vector_type(4)));

#define EPS 1e-5f

__device__ __forceinline__ short f2h(float x) {
    _Float16 h = (_Float16)x;   // round-to-nearest-even v_cvt_f16_f32
    union { _Float16 h; short s; } u;
    u.h = h;
    return u.s;
}

// ---------------------------------------------------------------------------
// prep: transpose+convert Wm -> WtM[l][f][k] fp16, Wl -> WtF[f][k] fp16 (f padded
// to 48 with zeros), zero the stats buffers. Runs every call (ws is re-poisoned).
// ---------------------------------------------------------------------------
__global__ void prep_kernel(const float* __restrict__ Wm, const float* __restrict__ Wl,
                            short* __restrict__ WtM, short* __restrict__ WtF,
                            float* __restrict__ stats) {
    const long T1 = 14L * 896 * 128;
    const long T2 = 48L * 896;
    const long T3 = 15L * 256;
    long i = (long)blockIdx.x * blockDim.x + threadIdx.x;
    if (i < T1) {
        long l = i / (896 * 128);
        long r = i % (896 * 128);
        long k = r >> 7;
        long f = r & 127;
        WtM[l * 114688 + f * 896 + k] = f2h(Wm[i]);
    } else if (i < T1 + T2) {
        long j = i - T1;
        long f = j / 896;
        long k = j % 896;
        WtF[j] = (f < 36) ? f2h(Wl[k * 36 + f]) : (short)0;
    } else if (i < T1 + T2 + T3) {
        stats[i - T1 - T2] = 0.0f;
    }
}

// ---------------------------------------------------------------------------
// layer0: h_lin[n,f] = b0[f] + sum_{k<21} x[idx[n,k/3], k%3] * W0[k,f]
// plus per-feature sum / sumsq accumulation. 16-node tiles, 1 barrier pair per
// tile. All fp32 — exact.
// ---------------------------------------------------------------------------
#define L0_NB 16
__global__ __launch_bounds__(256) void layer0_kernel(
        const float* __restrict__ x, const int* __restrict__ idx,
        const float* __restrict__ W0, const float* __restrict__ b0,
        float* __restrict__ hlin, float* __restrict__ stats, int N) {
    __shared__ float sW[21 * 128];
    __shared__ float sX[L0_NB * 21];
    __shared__ float sStat[256];
    const int tid = threadIdx.x;
    for (int i = tid; i < 21 * 128; i += 256) sW[i] = W0[i];
    const int f = tid & 127;
    const int half = tid >> 7;
    const float bf = b0[f];
    float s = 0.f, ss = 0.f;
    const int ntiles = (N + L0_NB - 1) / L0_NB;
    for (int t = blockIdx.x; t < ntiles; t += gridDim.x) {
        const int n0 = t * L0_NB;
        __syncthreads();
        for (int i = tid; i < L0_NB * 21; i += 256) {
            int ni = i / 21;
            int k = i - ni * 21;
            int j = k / 3;
            int c = k - j * 3;
            int n = n0 + ni;
            if (n >= N) n = N - 1;
            sX[i] = x[(long)idx[n * 7 + j] * 3 + c];
        }
        __syncthreads();
#pragma unroll
        for (int ni = 0; ni < 8; ++ni) {
            int node = n0 + half * 8 + ni;
            if (node >= N) break;   // per-thread, no barrier inside
            float acc = bf;
#pragma unroll
            for (int k = 0; k < 21; ++k)
                acc = fmaf(sX[(half * 8 + ni) * 21 + k], sW[k * 128 + f], acc);
            hlin[(long)node * 128 + f] = acc;
            s += acc;
            ss += acc * acc;
        }
    }
    __syncthreads();
    if (half == 1) { sStat[f] = s; sStat[128 + f] = ss; }
    __syncthreads();
    if (half == 0) {
        atomicAdd(&stats[f], s + sStat[f]);
        atomicAdd(&stats[128 + f], ss + sStat[128 + f]);
    }
}

// ---------------------------------------------------------------------------
// gemm_mid (BN-fused, software-pipelined, 512-thread / 8-wave blocks):
//   Same proven tile as the 49.4us version (64 nodes x 128 feats, sB in LDS,
//   depth-1 register prefetch of A+B), but 8 waves/block so 3 resident blocks
//   = 24 waves/CU (was 12) to hide the ~700cy gather latency via TLP.
//   Per-thread staging state halves -> VGPR target <=85 (launch_bounds(512,6)).
//   idx hoisted to LDS (aliased into sAux: 448 floats) so the per-phase chain
//   is ds_read->gather instead of idx-load->gather. LDS total 54,016B -> still
//   3 blocks/CU (3x54,016 <= 160KiB).
// Wave w: node quarter wm=w&3 (16 nodes), feat half wf=w>>2 (64 feats);
// acc[4 ni] of f32x4. Numerically identical op order to the previous version.
// ---------------------------------------------------------------------------
__global__ __launch_bounds__(512, 6) void gemm_mid_kernel(
        const float* __restrict__ hprev, const int* __restrict__ idx,
        const short* __restrict__ Wt, const float* __restrict__ bvec,
        const float* __restrict__ g, const float* __restrict__ be,
        const float* __restrict__ statsIn,
        float* __restrict__ hlin, float* __restrict__ statsOut,
        int N, float invN) {
    __shared__ short sA[64 * 136];   // [node][k] for current j (+8 pad)
    __shared__ short sB[128 * 136];  // [feat][k] for current j (+8 pad)
    __shared__ float sAux[448];      // sc|sh -> sIdx(448 ints) -> stats(256)

    const int tid = threadIdx.x;
    const int wave = tid >> 6;
    const int lane = tid & 63;
    const int quad = lane >> 4;
    const int l16 = lane & 15;
    const int wm = wave & 3;        // node quarter (16 nodes)
    const int wf = wave >> 2;       // feat half (64 feats)
    const int m0 = blockIdx.x * 64;
    const int t16 = tid >> 4;       // 0..31: staging row group
    const int fb = (tid & 15) * 8;  // fixed k/feature chunk for staging

    // phase 1: BN scale/shift into sAux, read to registers
    if (tid < 128) {
        float mu = statsIn[tid] * invN;
        float var = statsIn[128 + tid] * invN - mu * mu;
        float rs = rsqrtf(var + EPS);
        float sc = g[tid] * rs;
        sAux[tid] = sc;
        sAux[128 + tid] = be[tid] - mu * sc;
    }
    __syncthreads();
    float scR[8], shR[8];
#pragma unroll
    for (int e = 0; e < 8; ++e) {
        scR[e] = sAux[fb + e];
        shR[e] = sAux[128 + fb + e];
    }
    __syncthreads();
    // phase 2: idx hoist into the same LDS space
    int* sIdx = (int*)sAux;
    if (tid < 448) {
        long gg = (long)m0 * 7 + tid;
        long mx = (long)N * 7 - 1;
        sIdx[tid] = idx[gg < mx ? gg : mx];
    }
    __syncthreads();

    f32x4 acc[4];
#pragma unroll
    for (int ni = 0; ni < 4; ++ni) {
        float bv0 = bvec[wf * 64 + ni * 16 + l16];
        acc[ni][0] = bv0; acc[ni][1] = bv0; acc[ni][2] = bv0; acc[ni][3] = bv0;
    }

    // staging rows for this thread (clamped only in the last block)
    const int e0 = (m0 + t16 < N)      ? t16      : (N - 1 - m0);
    const int e1 = (m0 + 32 + t16 < N) ? 32 + t16 : (N - 1 - m0);

    float4 av[4];   // A prefetch: 2 rows x 2 float4
    f16x8 bv[4];    // B prefetch: 4 chunks of 8 fp16

    auto issueA = [&](int j) {
        long r0 = sIdx[e0 * 7 + j];
        long r1 = sIdx[e1 * 7 + j];
        const float* s0 = &hprev[r0 * 128 + fb];
        const float* s1 = &hprev[r1 * 128 + fb];
        av[0] = *(const float4*)s0;
        av[1] = *(const float4*)(s0 + 4);
        av[2] = *(const float4*)s1;
        av[3] = *(const float4*)(s1 + 4);
    };
    auto issueB = [&](int j) {
#pragma unroll
        for (int it = 0; it < 4; ++it) {
            int ff = t16 + it * 32;
            bv[it] = *(const f16x8*)&Wt[(long)ff * 896 + j * 128 + fb];
        }
    };
    auto writeA = [&]() {
#pragma unroll
        for (int it = 0; it < 2; ++it) {
            int nl = t16 + it * 32;
            float4 v0 = av[2 * it], v1 = av[2 * it + 1];
            union { short sh8[8]; f16x8 v; } u;
            u.sh8[0] = f2h(fmaxf(fmaf(v0.x, scR[0], shR[0]), 0.f));
            u.sh8[1] = f2h(fmaxf(fmaf(v0.y, scR[1], shR[1]), 0.f));
            u.sh8[2] = f2h(fmaxf(fmaf(v0.z, scR[2], shR[2]), 0.f));
            u.sh8[3] = f2h(fmaxf(fmaf(v0.w, scR[3], shR[3]), 0.f));
            u.sh8[4] = f2h(fmaxf(fmaf(v1.x, scR[4], shR[4]), 0.f));
            u.sh8[5] = f2h(fmaxf(fmaf(v1.y, scR[5], shR[5]), 0.f));
            u.sh8[6] = f2h(fmaxf(fmaf(v1.z, scR[6], shR[6]), 0.f));
            u.sh8[7] = f2h(fmaxf(fmaf(v1.w, scR[7], shR[7]), 0.f));
            *(f16x8*)&sA[nl * 136 + fb] = u.v;
        }
    };
    auto writeB = [&]() {
#pragma unroll
        for (int it = 0; it < 4; ++it) {
            int ff = t16 + it * 32;
            *(f16x8*)&sB[ff * 136 + fb] = bv[it];
        }
    };

    issueB(0);
    issueA(0);

    for (int j = 0; j < 7; ++j) {
        __syncthreads();            // sA/sB free (previous MFMA done)
        writeB();                   // implicit vmcnt waits at first use
        writeA();
        if (j < 6) {                // issue j+1 BEFORE compute of j
            issueB(j + 1);
            issueA(j + 1);
        }
        __syncthreads();
#pragma unroll
        for (int k0 = 0; k0 < 128; k0 += 32) {
            f16x8 a = *(const f16x8*)&sA[(wm * 16 + l16) * 136 + k0 + quad * 8];
            f16x8 b[4];
#pragma unroll
            for (int ni = 0; ni < 4; ++ni)
                b[ni] = *(const f16x8*)&sB[(wf * 64 + ni * 16 + l16) * 136 + k0 + quad * 8];
#pragma unroll
            for (int ni = 0; ni < 4; ++ni)
                acc[ni] = __builtin_amdgcn_mfma_f32_16x16x32_f16(a, b[ni], acc[ni], 0, 0, 0);
        }
    }

    // epilogue: store h_lin fp32, accumulate per-feature stats (sAux reused)
    __syncthreads();
    if (tid < 256) sAux[tid] = 0.f;
    __syncthreads();
#pragma unroll
    for (int ni = 0; ni < 4; ++ni) {
        int feat = wf * 64 + ni * 16 + l16;
        float s = 0.f, ss = 0.f;
#pragma unroll
        for (int r = 0; r < 4; ++r) {
            int node = m0 + wm * 16 + quad * 4 + r;
            float v = acc[ni][r];
            if (node < N) {
                hlin[(long)node * 128 + feat] = v;
                s += v;
                ss += v * v;
            }
        }
        atomicAdd(&sAux[feat], s);
        atomicAdd(&sAux[128 + feat], ss);
    }
    __syncthreads();
    if (tid < 128) {
        atomicAdd(&statsOut[tid], sAux[tid]);
        atomicAdd(&statsOut[128 + tid], sAux[128 + tid]);
    }
}

// ---------------------------------------------------------------------------
// gemm_final (BN-fused, software-pipelined):
//   out[N,36] = gather7(relu(bn(hprev)))[N,896] @ Wl + bl
// WtF: [48][896] fp16 (feats 36..47 zero). Block: 64 nodes, wave = 16 nodes x 48 feats.
// ---------------------------------------------------------------------------
__global__ __launch_bounds__(256) void gemm_final_kernel(
        const float* __restrict__ hprev, const int* __restrict__ idx,
        const short* __restrict__ WtF, const float* __restrict__ bl,
        const float* __restrict__ g, const float* __restrict__ be,
        const float* __restrict__ statsIn,
        float* __restrict__ out, int N, float invN) {
    __shared__ short sA[64 * 136];
    __shared__ short sB[48 * 136];
    __shared__ float sAux[256];

    const int tid = threadIdx.x;
    const int wave = tid >> 6;
    const int lane = tid & 63;
    const int quad = lane >> 4;
    const int l16 = lane & 15;
    const int m0 = blockIdx.x * 64;
    const int t16 = tid >> 4;
    const int fb = (tid & 15) * 8;

    if (tid < 128) {
        float mu = statsIn[tid] * invN;
        float var = statsIn[128 + tid] * invN - mu * mu;
        float rs = rsqrtf(var + EPS);
        float sc = g[tid] * rs;
        sAux[tid] = sc;
        sAux[128 + tid] = be[tid] - mu * sc;
    }
    __syncthreads();
    float scR[8], shR[8];
#pragma unroll
    for (int e = 0; e < 8; ++e) {
        scR[e] = sAux[fb + e];
        shR[e] = sAux[128 + fb + e];
    }

    f32x4 acc[3];
#pragma unroll
    for (int ni = 0; ni < 3; ++ni) {
        int feat = ni * 16 + l16;
        float bv = (feat < 36) ? bl[feat] : 0.f;
        acc[ni][0] = bv; acc[ni][1] = bv; acc[ni][2] = bv; acc[ni][3] = bv;
    }

    float4 av[8];
    f16x8 bv[3];

    auto issueA = [&](int j) {
#pragma unroll
        for (int it = 0; it < 4; ++it) {
            int nl = t16 + it * 16;
            int n = m0 + nl;
            n = (n < N) ? n : (N - 1);
            long row = idx[n * 7 + j];
            const float* src = &hprev[row * 128 + fb];
            av[2 * it]     = *(const float4*)src;
            av[2 * it + 1] = *(const float4*)(src + 4);
        }
    };
    auto issueB = [&](int j) {
#pragma unroll
        for (int it = 0; it < 3; ++it) {
            int ff = t16 + it * 16;
            bv[it] = *(const f16x8*)&WtF[(long)ff * 896 + j * 128 + fb];
        }
    };
    auto writeA = [&]() {
#pragma unroll
        for (int it = 0; it < 4; ++it) {
            int nl = t16 + it * 16;
            float4 v0 = av[2 * it], v1 = av[2 * it + 1];
            union { short sh8[8]; f16x8 v; } u;
            u.sh8[0] = f2h(fmaxf(fmaf(v0.x, scR[0], shR[0]), 0.f));
            u.sh8[1] = f2h(fmaxf(fmaf(v0.y, scR[1], shR[1]), 0.f));
            u.sh8[2] = f2h(fmaxf(fmaf(v0.z, scR[2], shR[2]), 0.f));
            u.sh8[3] = f2h(fmaxf(fmaf(v0.w, scR[3], shR[3]), 0.f));
            u.sh8[4] = f2h(fmaxf(fmaf(v1.x, scR[4], shR[4]), 0.f));
            u.sh8[5] = f2h(fmaxf(fmaf(v1.y, scR[5], shR[5]), 0.f));
            u.sh8[6] = f2h(fmaxf(fmaf(v1.z, scR[6], shR[6]), 0.f));
            u.sh8[7] = f2h(fmaxf(fmaf(v1.w, scR[7], shR[7]), 0.f));
            *(f16x8*)&sA[nl * 136 + fb] = u.v;
        }
    };
    auto writeB = [&]() {
#pragma unroll
        for (int it = 0; it < 3; ++it) {
            int ff = t16 + it * 16;
            *(f16x8*)&sB[ff * 136 + fb] = bv[it];
        }
    };

    issueB(0);
    issueA(0);

    for (int j = 0; j < 7; ++j) {
        __syncthreads();
        writeB();
        writeA();
        if (j < 6) {
            issueB(j + 1);
            issueA(j + 1);
        }
        __syncthreads();
#pragma unroll
        for (int k0 = 0; k0 < 128; k0 += 32) {
            f16x8 a = *(const f16x8*)&sA[(wave * 16 + l16) * 136 + k0 + quad * 8];
            f16x8 b[3];
#pragma unroll
            for (int ni = 0; ni < 3; ++ni)
                b[ni] = *(const f16x8*)&sB[(ni * 16 + l16) * 136 + k0 + quad * 8];
#pragma unroll
            for (int ni = 0; ni < 3; ++ni)
                acc[ni] = __builtin_amdgcn_mfma_f32_16x16x32_f16(a, b[ni], acc[ni], 0, 0, 0);
        }
    }

#pragma unroll
    for (int ni = 0; ni < 3; ++ni) {
        int feat = ni * 16 + l16;
        if (feat < 36) {
#pragma unroll
            for (int r = 0; r < 4; ++r) {
                int node = m0 + wave * 16 + quad * 4 + r;
                if (node < N) out[(long)node * 36 + feat] = acc[ni][r];
            }
        }
    }
}

// ---------------------------------------------------------------------------
extern "C" void kernel_launch(void* const* d_in, const int* in_sizes, int n_in,
                              void* d_out, int out_size, void* d_ws, size_t ws_size,
                              hipStream_t stream) {
    const float* x   = (const float*)d_in[0];
    const int*   idx = (const int*)d_in[1];
    const float* W0  = (const float*)d_in[2];
    const float* b0  = (const float*)d_in[3];
    const float* g0  = (const float*)d_in[4];
    const float* be0 = (const float*)d_in[5];
    const float* Wm  = (const float*)d_in[6];
    const float* bm  = (const float*)d_in[7];
    const float* gm  = (const float*)d_in[8];
    const float* bem = (const float*)d_in[9];
    const float* Wl  = (const float*)d_in[10];
    const float* bl  = (const float*)d_in[11];
    float* out = (float*)d_out;

    const int N = in_sizes[0] / 3;          // 40962
    const float invN = 1.0f / (float)N;

    char* ws = (char*)d_ws;
    size_t off = 0;
    auto alloc = [&](size_t bytes) -> void* {
        void* p = ws + off;
        off = (off + bytes + 255) & ~(size_t)255;
        return p;
    };
    short* WtM   = (short*)alloc(14UL * 128 * 896 * 2);
    short* WtF   = (short*)alloc(48UL * 896 * 2);
    float* stats = (float*)alloc(15UL * 256 * 4);
    float* hlinA = (float*)alloc((size_t)N * 128 * 4);
    float* hlinB = (float*)alloc((size_t)N * 128 * 4);

    {
        long total = 14L * 896 * 128 + 48L * 896 + 15L * 256;
        int blocks = (int)((total + 255) / 256);
        prep_kernel<<<blocks, 256, 0, stream>>>(Wm, Wl, WtM, WtF, stats);
    }

    layer0_kernel<<<1280, 256, 0, stream>>>(x, idx, W0, b0, hlinA, stats, N);

    const int gblocks = (N + 63) / 64;      // 641 blocks of 512 threads
    float* hin = hlinA;
    float* hout = hlinB;
    const float* gPrev = g0;
    const float* bePrev = be0;
    for (int L = 0; L < 14; ++L) {
        gemm_mid_kernel<<<gblocks, 512, 0, stream>>>(
            hin, idx, WtM + (size_t)L * 128 * 896, bm + L * 128,
            gPrev, bePrev, stats + L * 256,
            hout, stats + (L + 1) * 256, N, invN);
        gPrev = gm + L * 128;
        bePrev = bem + L * 128;
        float* t = hin; hin = hout; hout = t;
    }

    gemm_final_kernel<<<gblocks, 256, 0, stream>>>(
        hin, idx, WtF, bl, gm + 13 * 128, bem + 13 * 128, stats + 14 * 256,
        out, N, invN);
}

// Round 5
// 899.269 us; speedup vs baseline: 1.4420x; 1.4420x over previous
//
#include <hip/hip_runtime.h>

typedef _Float16 f16x8 __attribute__((ext_vector_type(8)));
typedef float f32x4 __attribute__((ext_vector_type(4)));

#define EPS 1e-5f

__device__ __forceinline__ short f2h(float x) {
    _Float16 h = (_Float16)x;   // round-to-nearest-even v_cvt_f16_f32
    union { _Float16 h; short s; } u;
    u.h = h;
    return u.s;
}

// ---------------------------------------------------------------------------
// prep: transpose+convert Wm -> WtM[l][f][k] fp16, Wl -> WtF[f][k] fp16 (f padded
// to 48 with zeros), zero the stats buffers. Runs every call (ws is re-poisoned).
// ---------------------------------------------------------------------------
__global__ void prep_kernel(const float* __restrict__ Wm, const float* __restrict__ Wl,
                            short* __restrict__ WtM, short* __restrict__ WtF,
                            float* __restrict__ stats) {
    const long T1 = 14L * 896 * 128;
    const long T2 = 48L * 896;
    const long T3 = 15L * 256;
    long i = (long)blockIdx.x * blockDim.x + threadIdx.x;
    if (i < T1) {
        long l = i / (896 * 128);
        long r = i % (896 * 128);
        long k = r >> 7;
        long f = r & 127;
        WtM[l * 114688 + f * 896 + k] = f2h(Wm[i]);
    } else if (i < T1 + T2) {
        long j = i - T1;
        long f = j / 896;
        long k = j % 896;
        WtF[j] = (f < 36) ? f2h(Wl[k * 36 + f]) : (short)0;
    } else if (i < T1 + T2 + T3) {
        stats[i - T1 - T2] = 0.0f;
    }
}

// ---------------------------------------------------------------------------
// layer0: h_lin[n,f] = b0[f] + sum_{k<21} x[idx[n,k/3], k%3] * W0[k,f]
// plus per-feature sum / sumsq accumulation. 16-node tiles, 1 barrier pair per
// tile. All fp32 — exact.
// ---------------------------------------------------------------------------
#define L0_NB 16
__global__ __launch_bounds__(256) void layer0_kernel(
        const float* __restrict__ x, const int* __restrict__ idx,
        const float* __restrict__ W0, const float* __restrict__ b0,
        float* __restrict__ hlin, float* __restrict__ stats, int N) {
    __shared__ float sW[21 * 128];
    __shared__ float sX[L0_NB * 21];
    __shared__ float sStat[256];
    const int tid = threadIdx.x;
    for (int i = tid; i < 21 * 128; i += 256) sW[i] = W0[i];
    const int f = tid & 127;
    const int half = tid >> 7;
    const float bf = b0[f];
    float s = 0.f, ss = 0.f;
    const int ntiles = (N + L0_NB - 1) / L0_NB;
    for (int t = blockIdx.x; t < ntiles; t += gridDim.x) {
        const int n0 = t * L0_NB;
        __syncthreads();
        for (int i = tid; i < L0_NB * 21; i += 256) {
            int ni = i / 21;
            int k = i - ni * 21;
            int j = k / 3;
            int c = k - j * 3;
            int n = n0 + ni;
            if (n >= N) n = N - 1;
            sX[i] = x[(long)idx[n * 7 + j] * 3 + c];
        }
        __syncthreads();
#pragma unroll
        for (int ni = 0; ni < 8; ++ni) {
            int node = n0 + half * 8 + ni;
            if (node >= N) break;   // per-thread, no barrier inside
            float acc = bf;
#pragma unroll
            for (int k = 0; k < 21; ++k)
                acc = fmaf(sX[(half * 8 + ni) * 21 + k], sW[k * 128 + f], acc);
            hlin[(long)node * 128 + f] = acc;
            s += acc;
            ss += acc * acc;
        }
    }
    __syncthreads();
    if (half == 1) { sStat[f] = s; sStat[128 + f] = ss; }
    __syncthreads();
    if (half == 0) {
        atomicAdd(&stats[f], s + sStat[f]);
        atomicAdd(&stats[128 + f], ss + sStat[128 + f]);
    }
}

// ---------------------------------------------------------------------------
// gemm_mid (BN-fused, software-pipelined — R2-proven structure, 32-node tiles):
//   Identical pipeline to the 49.4us/dispatch version (sB staged in LDS,
//   depth-1 register prefetch of A+B issued BEFORE the MFMA phase), but tile
//   M halved to 32 nodes -> 1281 blocks so the grid can actually fill the
//   3-blocks/CU LDS ceiling (R2 measured 17% occupancy purely from 641-block
//   supply). B staging per compute doubles but B is L2-resident + prefetched.
//   LDS = 8704(sA) + 34816(sB) + 1024(sAux) + 896(sIdx) = 45.4KB -> 3 blocks/CU.
//   256 threads / 4 waves; wave = 16 nodes (wm=wave&1) x 64 feats (wf=wave>>1).
//   Numerically identical op order per output element to the R2 version.
// ---------------------------------------------------------------------------
__global__ __launch_bounds__(256, 3) void gemm_mid_kernel(
        const float* __restrict__ hprev, const int* __restrict__ idx,
        const short* __restrict__ Wt, const float* __restrict__ bvec,
        const float* __restrict__ g, const float* __restrict__ be,
        const float* __restrict__ statsIn,
        float* __restrict__ hlin, float* __restrict__ statsOut,
        int N, float invN) {
    __shared__ short sA[32 * 136];   // [node][k] for current j (+8 pad)
    __shared__ short sB[128 * 136];  // [feat][k] for current j (+8 pad)
    __shared__ float sAux[256];      // sc|sh during staging; stats scratch later
    __shared__ int   sIdx[224];      // 32 nodes x 7 neighbors

    const int tid = threadIdx.x;
    const int wave = tid >> 6;
    const int lane = tid & 63;
    const int quad = lane >> 4;
    const int l16 = lane & 15;
    const int wm = wave & 1;        // node half (16 nodes)
    const int wf = wave >> 1;       // feat half (64 feats)
    const int m0 = blockIdx.x * 32;
    const int t16 = tid >> 4;       // 0..15: staging row group
    const int fb = (tid & 15) * 8;  // fixed k/feature chunk for staging

    if (tid < 128) {
        float mu = statsIn[tid] * invN;
        float var = statsIn[128 + tid] * invN - mu * mu;
        float rs = rsqrtf(var + EPS);
        float sc = g[tid] * rs;
        sAux[tid] = sc;
        sAux[128 + tid] = be[tid] - mu * sc;
    }
    if (tid < 224) {
        long gg = (long)m0 * 7 + tid;
        long mx = (long)N * 7 - 1;
        sIdx[tid] = idx[gg < mx ? gg : mx];
    }
    __syncthreads();
    float scR[8], shR[8];
#pragma unroll
    for (int e = 0; e < 8; ++e) {
        scR[e] = sAux[fb + e];
        shR[e] = sAux[128 + fb + e];
    }

    f32x4 acc[4];
#pragma unroll
    for (int ni = 0; ni < 4; ++ni) {
        float bv0 = bvec[wf * 64 + ni * 16 + l16];
        acc[ni][0] = bv0; acc[ni][1] = bv0; acc[ni][2] = bv0; acc[ni][3] = bv0;
    }

    // staging rows for this thread (clamped only in the last block)
    const int e0 = (m0 + t16 < N)      ? t16      : (N - 1 - m0);
    const int e1 = (m0 + 16 + t16 < N) ? 16 + t16 : (N - 1 - m0);

    float4 av[4];   // A prefetch: 2 rows x 2 float4 (gathered fp32)
    f16x8 bv[8];    // B prefetch: 8 chunks of 8 fp16

    auto issueA = [&](int j) {
        long r0 = sIdx[e0 * 7 + j];
        long r1 = sIdx[e1 * 7 + j];
        const float* s0 = &hprev[r0 * 128 + fb];
        const float* s1 = &hprev[r1 * 128 + fb];
        av[0] = *(const float4*)s0;
        av[1] = *(const float4*)(s0 + 4);
        av[2] = *(const float4*)s1;
        av[3] = *(const float4*)(s1 + 4);
    };
    auto issueB = [&](int j) {
#pragma unroll
        for (int it = 0; it < 8; ++it) {
            int ff = t16 + it * 16;
            bv[it] = *(const f16x8*)&Wt[(long)ff * 896 + j * 128 + fb];
        }
    };
    auto writeA = [&]() {
#pragma unroll
        for (int it = 0; it < 2; ++it) {
            int nl = t16 + it * 16;
            float4 v0 = av[2 * it], v1 = av[2 * it + 1];
            union { short sh8[8]; f16x8 v; } u;
            u.sh8[0] = f2h(fmaxf(fmaf(v0.x, scR[0], shR[0]), 0.f));
            u.sh8[1] = f2h(fmaxf(fmaf(v0.y, scR[1], shR[1]), 0.f));
            u.sh8[2] = f2h(fmaxf(fmaf(v0.z, scR[2], shR[2]), 0.f));
            u.sh8[3] = f2h(fmaxf(fmaf(v0.w, scR[3], shR[3]), 0.f));
            u.sh8[4] = f2h(fmaxf(fmaf(v1.x, scR[4], shR[4]), 0.f));
            u.sh8[5] = f2h(fmaxf(fmaf(v1.y, scR[5], shR[5]), 0.f));
            u.sh8[6] = f2h(fmaxf(fmaf(v1.z, scR[6], shR[6]), 0.f));
            u.sh8[7] = f2h(fmaxf(fmaf(v1.w, scR[7], shR[7]), 0.f));
            *(f16x8*)&sA[nl * 136 + fb] = u.v;
        }
    };
    auto writeB = [&]() {
#pragma unroll
        for (int it = 0; it < 8; ++it) {
            int ff = t16 + it * 16;
            *(f16x8*)&sB[ff * 136 + fb] = bv[it];
        }
    };

    issueB(0);
    issueA(0);

    for (int j = 0; j < 7; ++j) {
        __syncthreads();            // sA/sB free (previous MFMA done)
        writeB();                   // implicit vmcnt waits at first use
        writeA();
        if (j < 6) {                // issue j+1 BEFORE compute of j
            issueB(j + 1);
            issueA(j + 1);
        }
        __syncthreads();
#pragma unroll
        for (int k0 = 0; k0 < 128; k0 += 32) {
            f16x8 a = *(const f16x8*)&sA[(wm * 16 + l16) * 136 + k0 + quad * 8];
            f16x8 b[4];
#pragma unroll
            for (int ni = 0; ni < 4; ++ni)
                b[ni] = *(const f16x8*)&sB[(wf * 64 + ni * 16 + l16) * 136 + k0 + quad * 8];
#pragma unroll
            for (int ni = 0; ni < 4; ++ni)
                acc[ni] = __builtin_amdgcn_mfma_f32_16x16x32_f16(a, b[ni], acc[ni], 0, 0, 0);
        }
    }

    // epilogue: store h_lin fp32, accumulate per-feature stats (sAux reused)
    __syncthreads();
    sAux[tid] = 0.f;
    __syncthreads();
#pragma unroll
    for (int ni = 0; ni < 4; ++ni) {
        int feat = wf * 64 + ni * 16 + l16;
        float s = 0.f, ss = 0.f;
#pragma unroll
        for (int r = 0; r < 4; ++r) {
            int node = m0 + wm * 16 + quad * 4 + r;
            float v = acc[ni][r];
            if (node < N) {
                hlin[(long)node * 128 + feat] = v;
                s += v;
                ss += v * v;
            }
        }
        atomicAdd(&sAux[feat], s);
        atomicAdd(&sAux[128 + feat], ss);
    }
    __syncthreads();
    if (tid < 128) {
        atomicAdd(&statsOut[tid], sAux[tid]);
        atomicAdd(&statsOut[128 + tid], sAux[128 + tid]);
    }
}

// ---------------------------------------------------------------------------
// gemm_final (BN-fused, software-pipelined):
//   out[N,36] = gather7(relu(bn(hprev)))[N,896] @ Wl + bl
// WtF: [48][896] fp16 (feats 36..47 zero). Block: 64 nodes, wave = 16 nodes x 48 feats.
// ---------------------------------------------------------------------------
__global__ __launch_bounds__(256) void gemm_final_kernel(
        const float* __restrict__ hprev, const int* __restrict__ idx,
        const short* __restrict__ WtF, const float* __restrict__ bl,
        const float* __restrict__ g, const float* __restrict__ be,
        const float* __restrict__ statsIn,
        float* __restrict__ out, int N, float invN) {
    __shared__ short sA[64 * 136];
    __shared__ short sB[48 * 136];
    __shared__ float sAux[256];

    const int tid = threadIdx.x;
    const int wave = tid >> 6;
    const int lane = tid & 63;
    const int quad = lane >> 4;
    const int l16 = lane & 15;
    const int m0 = blockIdx.x * 64;
    const int t16 = tid >> 4;
    const int fb = (tid & 15) * 8;

    if (tid < 128) {
        float mu = statsIn[tid] * invN;
        float var = statsIn[128 + tid] * invN - mu * mu;
        float rs = rsqrtf(var + EPS);
        float sc = g[tid] * rs;
        sAux[tid] = sc;
        sAux[128 + tid] = be[tid] - mu * sc;
    }
    __syncthreads();
    float scR[8], shR[8];
#pragma unroll
    for (int e = 0; e < 8; ++e) {
        scR[e] = sAux[fb + e];
        shR[e] = sAux[128 + fb + e];
    }

    f32x4 acc[3];
#pragma unroll
    for (int ni = 0; ni < 3; ++ni) {
        int feat = ni * 16 + l16;
        float bv = (feat < 36) ? bl[feat] : 0.f;
        acc[ni][0] = bv; acc[ni][1] = bv; acc[ni][2] = bv; acc[ni][3] = bv;
    }

    float4 av[8];
    f16x8 bv[3];

    auto issueA = [&](int j) {
#pragma unroll
        for (int it = 0; it < 4; ++it) {
            int nl = t16 + it * 16;
            int n = m0 + nl;
            n = (n < N) ? n : (N - 1);
            long row = idx[n * 7 + j];
            const float* src = &hprev[row * 128 + fb];
            av[2 * it]     = *(const float4*)src;
            av[2 * it + 1] = *(const float4*)(src + 4);
        }
    };
    auto issueB = [&](int j) {
#pragma unroll
        for (int it = 0; it < 3; ++it) {
            int ff = t16 + it * 16;
            bv[it] = *(const f16x8*)&WtF[(long)ff * 896 + j * 128 + fb];
        }
    };
    auto writeA = [&]() {
#pragma unroll
        for (int it = 0; it < 4; ++it) {
            int nl = t16 + it * 16;
            float4 v0 = av[2 * it], v1 = av[2 * it + 1];
            union { short sh8[8]; f16x8 v; } u;
            u.sh8[0] = f2h(fmaxf(fmaf(v0.x, scR[0], shR[0]), 0.f));
            u.sh8[1] = f2h(fmaxf(fmaf(v0.y, scR[1], shR[1]), 0.f));
            u.sh8[2] = f2h(fmaxf(fmaf(v0.z, scR[2], shR[2]), 0.f));
            u.sh8[3] = f2h(fmaxf(fmaf(v0.w, scR[3], shR[3]), 0.f));
            u.sh8[4] = f2h(fmaxf(fmaf(v1.x, scR[4], shR[4]), 0.f));
            u.sh8[5] = f2h(fmaxf(fmaf(v1.y, scR[5], shR[5]), 0.f));
            u.sh8[6] = f2h(fmaxf(fmaf(v1.z, scR[6], shR[6]), 0.f));
            u.sh8[7] = f2h(fmaxf(fmaf(v1.w, scR[7], shR[7]), 0.f));
            *(f16x8*)&sA[nl * 136 + fb] = u.v;
        }
    };
    auto writeB = [&]() {
#pragma unroll
        for (int it = 0; it < 3; ++it) {
            int ff = t16 + it * 16;
            *(f16x8*)&sB[ff * 136 + fb] = bv[it];
        }
    };

    issueB(0);
    issueA(0);

    for (int j = 0; j < 7; ++j) {
        __syncthreads();
        writeB();
        writeA();
        if (j < 6) {
            issueB(j + 1);
            issueA(j + 1);
        }
        __syncthreads();
#pragma unroll
        for (int k0 = 0; k0 < 128; k0 += 32) {
            f16x8 a = *(const f16x8*)&sA[(wave * 16 + l16) * 136 + k0 + quad * 8];
            f16x8 b[3];
#pragma unroll
            for (int ni = 0; ni < 3; ++ni)
                b[ni] = *(const f16x8*)&sB[(ni * 16 + l16) * 136 + k0 + quad * 8];
#pragma unroll
            for (int ni = 0; ni < 3; ++ni)
                acc[ni] = __builtin_amdgcn_mfma_f32_16x16x32_f16(a, b[ni], acc[ni], 0, 0, 0);
        }
    }

#pragma unroll
    for (int ni = 0; ni < 3; ++ni) {
        int feat = ni * 16 + l16;
        if (feat < 36) {
#pragma unroll
            for (int r = 0; r < 4; ++r) {
                int node = m0 + wave * 16 + quad * 4 + r;
                if (node < N) out[(long)node * 36 + feat] = acc[ni][r];
            }
        }
    }
}

// ---------------------------------------------------------------------------
extern "C" void kernel_launch(void* const* d_in, const int* in_sizes, int n_in,
                              void* d_out, int out_size, void* d_ws, size_t ws_size,
                              hipStream_t stream) {
    const float* x   = (const float*)d_in[0];
    const int*   idx = (const int*)d_in[1];
    const float* W0  = (const float*)d_in[2];
    const float* b0  = (const float*)d_in[3];
    const float* g0  = (const float*)d_in[4];
    const float* be0 = (const float*)d_in[5];
    const float* Wm  = (const float*)d_in[6];
    const float* bm  = (const float*)d_in[7];
    const float* gm  = (const float*)d_in[8];
    const float* bem = (const float*)d_in[9];
    const float* Wl  = (const float*)d_in[10];
    const float* bl  = (const float*)d_in[11];
    float* out = (float*)d_out;

    const int N = in_sizes[0] / 3;          // 40962
    const float invN = 1.0f / (float)N;

    char* ws = (char*)d_ws;
    size_t off = 0;
    auto alloc = [&](size_t bytes) -> void* {
        void* p = ws + off;
        off = (off + bytes + 255) & ~(size_t)255;
        return p;
    };
    short* WtM   = (short*)alloc(14UL * 128 * 896 * 2);
    short* WtF   = (short*)alloc(48UL * 896 * 2);
    float* stats = (float*)alloc(15UL * 256 * 4);
    float* hlinA = (float*)alloc((size_t)N * 128 * 4);
    float* hlinB = (float*)alloc((size_t)N * 128 * 4);

    {
        long total = 14L * 896 * 128 + 48L * 896 + 15L * 256;
        int blocks = (int)((total + 255) / 256);
        prep_kernel<<<blocks, 256, 0, stream>>>(Wm, Wl, WtM, WtF, stats);
    }

    layer0_kernel<<<1280, 256, 0, stream>>>(x, idx, W0, b0, hlinA, stats, N);

    const int gblocks_mid = (N + 31) / 32;   // 1281 blocks -> fills 3 blocks/CU
    float* hin = hlinA;
    float* hout = hlinB;
    const float* gPrev = g0;
    const float* bePrev = be0;
    for (int L = 0; L < 14; ++L) {
        gemm_mid_kernel<<<gblocks_mid, 256, 0, stream>>>(
            hin, idx, WtM + (size_t)L * 128 * 896, bm + L * 128,
            gPrev, bePrev, stats + L * 256,
            hout, stats + (L + 1) * 256, N, invN);
        gPrev = gm + L * 128;
        bePrev = bem + L * 128;
        float* t = hin; hin = hout; hout = t;
    }

    const int gblocks_fin = (N + 63) / 64;
    gemm_final_kernel<<<gblocks_fin, 256, 0, stream>>>(
        hin, idx, WtF, bl, gm + 13 * 128, bem + 13 * 128, stats + 14 * 256,
        out, N, invN);
}

// Round 6
// 733.701 us; speedup vs baseline: 1.7674x; 1.2257x over previous
//
#include <hip/hip_runtime.h>

typedef _Float16 f16x8 __attribute__((ext_vector_type(8)));
typedef float f32x4 __attribute__((ext_vector_type(4)));

#define EPS 1e-5f

__device__ __forceinline__ short f2h(float x) {
    _Float16 h = (_Float16)x;   // round-to-nearest-even v_cvt_f16_f32
    union { _Float16 h; short s; } u;
    u.h = h;
    return u.s;
}

// ---------------------------------------------------------------------------
// prep: transpose+convert Wm -> WtM[l][f][k] fp16, Wl -> WtF[f][k] fp16 (f padded
// to 48 with zeros), zero the stats buffers. Runs every call (ws is re-poisoned).
// ---------------------------------------------------------------------------
__global__ void prep_kernel(const float* __restrict__ Wm, const float* __restrict__ Wl,
                            short* __restrict__ WtM, short* __restrict__ WtF,
                            float* __restrict__ stats) {
    const long T1 = 14L * 896 * 128;
    const long T2 = 48L * 896;
    const long T3 = 15L * 256;
    long i = (long)blockIdx.x * blockDim.x + threadIdx.x;
    if (i < T1) {
        long l = i / (896 * 128);
        long r = i % (896 * 128);
        long k = r >> 7;
        long f = r & 127;
        WtM[l * 114688 + f * 896 + k] = f2h(Wm[i]);
    } else if (i < T1 + T2) {
        long j = i - T1;
        long f = j / 896;
        long k = j % 896;
        WtF[j] = (f < 36) ? f2h(Wl[k * 36 + f]) : (short)0;
    } else if (i < T1 + T2 + T3) {
        stats[i - T1 - T2] = 0.0f;
    }
}

// ---------------------------------------------------------------------------
// layer0: h[n,f] = b0[f] + sum_{k<21} x[idx[n,k/3], k%3] * W0[k,f]
// Output stored as fp16 (pre-BN); per-feature sum/sumsq computed from the
// exact fp32 accumulator. 16-node tiles, 1 barrier pair per tile.
// ---------------------------------------------------------------------------
#define L0_NB 16
__global__ __launch_bounds__(256) void layer0_kernel(
        const float* __restrict__ x, const int* __restrict__ idx,
        const float* __restrict__ W0, const float* __restrict__ b0,
        short* __restrict__ hlin, float* __restrict__ stats, int N) {
    __shared__ float sW[21 * 128];
    __shared__ float sX[L0_NB * 21];
    __shared__ float sStat[256];
    const int tid = threadIdx.x;
    for (int i = tid; i < 21 * 128; i += 256) sW[i] = W0[i];
    const int f = tid & 127;
    const int half = tid >> 7;
    const float bf = b0[f];
    float s = 0.f, ss = 0.f;
    const int ntiles = (N + L0_NB - 1) / L0_NB;
    for (int t = blockIdx.x; t < ntiles; t += gridDim.x) {
        const int n0 = t * L0_NB;
        __syncthreads();
        for (int i = tid; i < L0_NB * 21; i += 256) {
            int ni = i / 21;
            int k = i - ni * 21;
            int j = k / 3;
            int c = k - j * 3;
            int n = n0 + ni;
            if (n >= N) n = N - 1;
            sX[i] = x[(long)idx[n * 7 + j] * 3 + c];
        }
        __syncthreads();
#pragma unroll
        for (int ni = 0; ni < 8; ++ni) {
            int node = n0 + half * 8 + ni;
            if (node >= N) break;   // per-thread, no barrier inside
            float acc = bf;
#pragma unroll
            for (int k = 0; k < 21; ++k)
                acc = fmaf(sX[(half * 8 + ni) * 21 + k], sW[k * 128 + f], acc);
            hlin[(long)node * 128 + f] = f2h(acc);
            s += acc;
            ss += acc * acc;
        }
    }
    __syncthreads();
    if (half == 1) { sStat[f] = s; sStat[128 + f] = ss; }
    __syncthreads();
    if (half == 0) {
        atomicAdd(&stats[f], s + sStat[f]);
        atomicAdd(&stats[128 + f], ss + sStat[128 + f]);
    }
}

// ---------------------------------------------------------------------------
// gemm_mid (BN-fused, software-pipelined — exact R2 structure, fp16 h-buffer):
//   input rows gathered as fp16 (256B/row, HALF the L2-miss traffic of fp32),
//   converted to fp32, BN+ReLU applied (fp32-exact scale/shift from stats),
//   rounded to f16 into sA. Depth-1 register prefetch of A+B issued BEFORE
//   the MFMA phase of tile j (proven live at VGPR 80 in the 49.4us version;
//   A-prefetch now 16 VGPR instead of 32).
//   Output h stored fp16 (pre-BN); stats from exact fp32 accumulators.
// Block: 256 thr = 4 waves, tile 64 nodes x 128 feats; wave = 32 nodes x 64 feats.
// LDS 53,248B -> 3 blocks/CU.
// ---------------------------------------------------------------------------
__global__ __launch_bounds__(256, 3) void gemm_mid_kernel(
        const short* __restrict__ hprev, const int* __restrict__ idx,
        const short* __restrict__ Wt, const float* __restrict__ bvec,
        const float* __restrict__ g, const float* __restrict__ be,
        const float* __restrict__ statsIn,
        short* __restrict__ hlin, float* __restrict__ statsOut,
        int N, float invN) {
    __shared__ short sA[64 * 136];   // [node][k] for current j
    __shared__ short sB[128 * 136];  // [feat][k] for current j
    __shared__ float sAux[256];      // sc|sh during staging; stats scratch later

    const int tid = threadIdx.x;
    const int wave = tid >> 6;
    const int lane = tid & 63;
    const int quad = lane >> 4;
    const int l16 = lane & 15;
    const int wm = wave & 1;        // node half (32 nodes)
    const int wf = wave >> 1;       // feat half (64 feats)
    const int m0 = blockIdx.x * 64;
    const int t16 = tid >> 4;       // 0..15: staging row group
    const int fb = (tid & 15) * 8;  // fixed k/feature chunk for staging

    if (tid < 128) {
        float mu = statsIn[tid] * invN;
        float var = statsIn[128 + tid] * invN - mu * mu;
        float rs = rsqrtf(var + EPS);
        float sc = g[tid] * rs;
        sAux[tid] = sc;
        sAux[128 + tid] = be[tid] - mu * sc;
    }
    __syncthreads();
    float scR[8], shR[8];
#pragma unroll
    for (int e = 0; e < 8; ++e) {
        scR[e] = sAux[fb + e];
        shR[e] = sAux[128 + fb + e];
    }

    f32x4 acc[2][4];
#pragma unroll
    for (int ni = 0; ni < 4; ++ni) {
        float bv0 = bvec[wf * 64 + ni * 16 + l16];
#pragma unroll
        for (int mi = 0; mi < 2; ++mi) {
            acc[mi][ni][0] = bv0; acc[mi][ni][1] = bv0; acc[mi][ni][2] = bv0; acc[mi][ni][3] = bv0;
        }
    }

    f16x8 av[4];    // A prefetch: 4 gathered fp16 row-chunks (16B each)
    f16x8 bv[8];    // B prefetch: 8 chunks of 8 fp16

    // --- issue loads for tile j into av/bv -------------------------------
    auto issueA = [&](int j) {
#pragma unroll
        for (int it = 0; it < 4; ++it) {
            int nl = t16 + it * 16;
            int n = m0 + nl;
            n = (n < N) ? n : (N - 1);
            long row = idx[n * 7 + j];
            av[it] = *(const f16x8*)&hprev[row * 128 + fb];
        }
    };
    auto issueB = [&](int j) {
#pragma unroll
        for (int it = 0; it < 8; ++it) {
            int ff = t16 + it * 16;
            bv[it] = *(const f16x8*)&Wt[(long)ff * 896 + j * 128 + fb];
        }
    };
    // --- consume av/bv -> LDS (cvt + BN + ReLU + f16 on A) ---------------
    auto writeA = [&]() {
#pragma unroll
        for (int it = 0; it < 4; ++it) {
            int nl = t16 + it * 16;
            f16x8 hv = av[it];
            union { short sh8[8]; f16x8 v; } u;
#pragma unroll
            for (int e = 0; e < 8; ++e) {
                float v = (float)hv[e];
                u.sh8[e] = f2h(fmaxf(fmaf(v, scR[e], shR[e]), 0.f));
            }
            *(f16x8*)&sA[nl * 136 + fb] = u.v;
        }
    };
    auto writeB = [&]() {
#pragma unroll
        for (int it = 0; it < 8; ++it) {
            int ff = t16 + it * 16;
            *(f16x8*)&sB[ff * 136 + fb] = bv[it];
        }
    };

    issueB(0);
    issueA(0);

    for (int j = 0; j < 7; ++j) {
        __syncthreads();            // sA/sB free (previous MFMA done)
        writeB();                   // implicit vmcnt waits at first use
        writeA();
        if (j < 6) {                // issue j+1 BEFORE compute of j
            issueB(j + 1);
            issueA(j + 1);
        }
        __syncthreads();
#pragma unroll
        for (int k0 = 0; k0 < 128; k0 += 32) {
            f16x8 a[2], b[4];
#pragma unroll
            for (int mi = 0; mi < 2; ++mi)
                a[mi] = *(const f16x8*)&sA[(wm * 32 + mi * 16 + l16) * 136 + k0 + quad * 8];
#pragma unroll
            for (int ni = 0; ni < 4; ++ni)
                b[ni] = *(const f16x8*)&sB[(wf * 64 + ni * 16 + l16) * 136 + k0 + quad * 8];
#pragma unroll
            for (int mi = 0; mi < 2; ++mi)
#pragma unroll
                for (int ni = 0; ni < 4; ++ni)
                    acc[mi][ni] = __builtin_amdgcn_mfma_f32_16x16x32_f16(a[mi], b[ni], acc[mi][ni], 0, 0, 0);
        }
    }

    // epilogue: store h fp16 (pre-BN), accumulate per-feature fp32 stats
    __syncthreads();
    sAux[tid] = 0.f;
    __syncthreads();
#pragma unroll
    for (int mi = 0; mi < 2; ++mi) {
#pragma unroll
        for (int ni = 0; ni < 4; ++ni) {
            int feat = wf * 64 + ni * 16 + l16;
            float s = 0.f, ss = 0.f;
#pragma unroll
            for (int r = 0; r < 4; ++r) {
                int node = m0 + wm * 32 + mi * 16 + quad * 4 + r;
                float v = acc[mi][ni][r];
                if (node < N) {
                    hlin[(long)node * 128 + feat] = f2h(v);
                    s += v;
                    ss += v * v;
                }
            }
            atomicAdd(&sAux[feat], s);
            atomicAdd(&sAux[128 + feat], ss);
        }
    }
    __syncthreads();
    if (tid < 128) {
        atomicAdd(&statsOut[tid], sAux[tid]);
        atomicAdd(&statsOut[128 + tid], sAux[128 + tid]);
    }
}

// ---------------------------------------------------------------------------
// gemm_final (BN-fused, software-pipelined, fp16 h gather):
//   out[N,36] = gather7(relu(bn(hprev)))[N,896] @ Wl + bl
// WtF: [48][896] fp16 (feats 36..47 zero). Block: 64 nodes, wave = 16 nodes x 48 feats.
// ---------------------------------------------------------------------------
__global__ __launch_bounds__(256) void gemm_final_kernel(
        const short* __restrict__ hprev, const int* __restrict__ idx,
        const short* __restrict__ WtF, const float* __restrict__ bl,
        const float* __restrict__ g, const float* __restrict__ be,
        const float* __restrict__ statsIn,
        float* __restrict__ out, int N, float invN) {
    __shared__ short sA[64 * 136];
    __shared__ short sB[48 * 136];
    __shared__ float sAux[256];

    const int tid = threadIdx.x;
    const int wave = tid >> 6;
    const int lane = tid & 63;
    const int quad = lane >> 4;
    const int l16 = lane & 15;
    const int m0 = blockIdx.x * 64;
    const int t16 = tid >> 4;
    const int fb = (tid & 15) * 8;

    if (tid < 128) {
        float mu = statsIn[tid] * invN;
        float var = statsIn[128 + tid] * invN - mu * mu;
        float rs = rsqrtf(var + EPS);
        float sc = g[tid] * rs;
        sAux[tid] = sc;
        sAux[128 + tid] = be[tid] - mu * sc;
    }
    __syncthreads();
    float scR[8], shR[8];
#pragma unroll
    for (int e = 0; e < 8; ++e) {
        scR[e] = sAux[fb + e];
        shR[e] = sAux[128 + fb + e];
    }

    f32x4 acc[3];
#pragma unroll
    for (int ni = 0; ni < 3; ++ni) {
        int feat = ni * 16 + l16;
        float bv0 = (feat < 36) ? bl[feat] : 0.f;
        acc[ni][0] = bv0; acc[ni][1] = bv0; acc[ni][2] = bv0; acc[ni][3] = bv0;
    }

    f16x8 av[4];
    f16x8 bv[3];

    auto issueA = [&](int j) {
#pragma unroll
        for (int it = 0; it < 4; ++it) {
            int nl = t16 + it * 16;
            int n = m0 + nl;
            n = (n < N) ? n : (N - 1);
            long row = idx[n * 7 + j];
            av[it] = *(const f16x8*)&hprev[row * 128 + fb];
        }
    };
    auto issueB = [&](int j) {
#pragma unroll
        for (int it = 0; it < 3; ++it) {
            int ff = t16 + it * 16;
            bv[it] = *(const f16x8*)&WtF[(long)ff * 896 + j * 128 + fb];
        }
    };
    auto writeA = [&]() {
#pragma unroll
        for (int it = 0; it < 4; ++it) {
            int nl = t16 + it * 16;
            f16x8 hv = av[it];
            union { short sh8[8]; f16x8 v; } u;
#pragma unroll
            for (int e = 0; e < 8; ++e) {
                float v = (float)hv[e];
                u.sh8[e] = f2h(fmaxf(fmaf(v, scR[e], shR[e]), 0.f));
            }
            *(f16x8*)&sA[nl * 136 + fb] = u.v;
        }
    };
    auto writeB = [&]() {
#pragma unroll
        for (int it = 0; it < 3; ++it) {
            int ff = t16 + it * 16;
            *(f16x8*)&sB[ff * 136 + fb] = bv[it];
        }
    };

    issueB(0);
    issueA(0);

    for (int j = 0; j < 7; ++j) {
        __syncthreads();
        writeB();
        writeA();
        if (j < 6) {
            issueB(j + 1);
            issueA(j + 1);
        }
        __syncthreads();
#pragma unroll
        for (int k0 = 0; k0 < 128; k0 += 32) {
            f16x8 a = *(const f16x8*)&sA[(wave * 16 + l16) * 136 + k0 + quad * 8];
            f16x8 b[3];
#pragma unroll
            for (int ni = 0; ni < 3; ++ni)
                b[ni] = *(const f16x8*)&sB[(ni * 16 + l16) * 136 + k0 + quad * 8];
#pragma unroll
            for (int ni = 0; ni < 3; ++ni)
                acc[ni] = __builtin_amdgcn_mfma_f32_16x16x32_f16(a, b[ni], acc[ni], 0, 0, 0);
        }
    }

#pragma unroll
    for (int ni = 0; ni < 3; ++ni) {
        int feat = ni * 16 + l16;
        if (feat < 36) {
#pragma unroll
            for (int r = 0; r < 4; ++r) {
                int node = m0 + wave * 16 + quad * 4 + r;
                if (node < N) out[(long)node * 36 + feat] = acc[ni][r];
            }
        }
    }
}

// ---------------------------------------------------------------------------
extern "C" void kernel_launch(void* const* d_in, const int* in_sizes, int n_in,
                              void* d_out, int out_size, void* d_ws, size_t ws_size,
                              hipStream_t stream) {
    const float* x   = (const float*)d_in[0];
    const int*   idx = (const int*)d_in[1];
    const float* W0  = (const float*)d_in[2];
    const float* b0  = (const float*)d_in[3];
    const float* g0  = (const float*)d_in[4];
    const float* be0 = (const float*)d_in[5];
    const float* Wm  = (const float*)d_in[6];
    const float* bm  = (const float*)d_in[7];
    const float* gm  = (const float*)d_in[8];
    const float* bem = (const float*)d_in[9];
    const float* Wl  = (const float*)d_in[10];
    const float* bl  = (const float*)d_in[11];
    float* out = (float*)d_out;

    const int N = in_sizes[0] / 3;          // 40962
    const float invN = 1.0f / (float)N;

    char* ws = (char*)d_ws;
    size_t off = 0;
    auto alloc = [&](size_t bytes) -> void* {
        void* p = ws + off;
        off = (off + bytes + 255) & ~(size_t)255;
        return p;
    };
    short* WtM   = (short*)alloc(14UL * 128 * 896 * 2);
    short* WtF   = (short*)alloc(48UL * 896 * 2);
    float* stats = (float*)alloc(15UL * 256 * 4);
    short* hlinA = (short*)alloc((size_t)N * 128 * 2);
    short* hlinB = (short*)alloc((size_t)N * 128 * 2);

    {
        long total = 14L * 896 * 128 + 48L * 896 + 15L * 256;
        int blocks = (int)((total + 255) / 256);
        prep_kernel<<<blocks, 256, 0, stream>>>(Wm, Wl, WtM, WtF, stats);
    }

    layer0_kernel<<<1280, 256, 0, stream>>>(x, idx, W0, b0, hlinA, stats, N);

    const int gblocks = (N + 63) / 64;      // 641 blocks, proven R2 geometry
    short* hin = hlinA;
    short* hout = hlinB;
    const float* gPrev = g0;
    const float* bePrev = be0;
    for (int L = 0; L < 14; ++L) {
        gemm_mid_kernel<<<gblocks, 256, 0, stream>>>(
            hin, idx, WtM + (size_t)L * 128 * 896, bm + L * 128,
            gPrev, bePrev, stats + L * 256,
            hout, stats + (L + 1) * 256, N, invN);
        gPrev = gm + L * 128;
        bePrev = bem + L * 128;
        short* t = hin; hin = hout; hout = t;
    }

    gemm_final_kernel<<<gblocks, 256, 0, stream>>>(
        hin, idx, WtF, bl, gm + 13 * 128, bem + 13 * 128, stats + 14 * 256,
        out, N, invN);
}

// Round 7
// 641.320 us; speedup vs baseline: 2.0220x; 1.1440x over previous
//
#include <hip/hip_runtime.h>

typedef _Float16 f16x8 __attribute__((ext_vector_type(8)));
typedef float f32x4 __attribute__((ext_vector_type(4)));

#define EPS 1e-5f

__device__ __forceinline__ short f2h(float x) {
    _Float16 h = (_Float16)x;   // round-to-nearest-even v_cvt_f16_f32
    union { _Float16 h; short s; } u;
    u.h = h;
    return u.s;
}

// ---------------------------------------------------------------------------
// prep: transpose+convert Wm -> WtM[l][f][k] fp16, Wl -> WtF[f][k] fp16 (f padded
// to 48 with zeros), zero the stats buffers. Runs every call (ws is re-poisoned).
// ---------------------------------------------------------------------------
__global__ void prep_kernel(const float* __restrict__ Wm, const float* __restrict__ Wl,
                            short* __restrict__ WtM, short* __restrict__ WtF,
                            float* __restrict__ stats) {
    const long T1 = 14L * 896 * 128;
    const long T2 = 48L * 896;
    const long T3 = 15L * 256;
    long i = (long)blockIdx.x * blockDim.x + threadIdx.x;
    if (i < T1) {
        long l = i / (896 * 128);
        long r = i % (896 * 128);
        long k = r >> 7;
        long f = r & 127;
        WtM[l * 114688 + f * 896 + k] = f2h(Wm[i]);
    } else if (i < T1 + T2) {
        long j = i - T1;
        long f = j / 896;
        long k = j % 896;
        WtF[j] = (f < 36) ? f2h(Wl[k * 36 + f]) : (short)0;
    } else if (i < T1 + T2 + T3) {
        stats[i - T1 - T2] = 0.0f;
    }
}

// ---------------------------------------------------------------------------
// layer0: h[n,f] = b0[f] + sum_{k<21} x[idx[n,k/3], k%3] * W0[k,f]
// W held in 21 REGISTERS per thread (f fixed per thread; W0[k*128+f] is
// thread-invariant) -> inner loop is 1 broadcast LDS read + 1 FMA instead of
// 2 LDS reads + 1 FMA. Previous version was LDS-read-throughput-bound
// (46us, VALUBusy 9.5%, FETCH 2.6MB). One 16-node tile per block, grid=ntiles.
// fp32 math order unchanged; output fp16 (pre-BN) + exact fp32 stats.
// ---------------------------------------------------------------------------
#define L0_NB 16
__global__ __launch_bounds__(256) void layer0_kernel(
        const float* __restrict__ x, const int* __restrict__ idx,
        const float* __restrict__ W0, const float* __restrict__ b0,
        short* __restrict__ hlin, float* __restrict__ stats, int N) {
    __shared__ float sX[L0_NB * 21];
    __shared__ float sStat[256];
    const int tid = threadIdx.x;
    const int f = tid & 127;
    const int half = tid >> 7;
    float wreg[21];
#pragma unroll
    for (int k = 0; k < 21; ++k) wreg[k] = W0[k * 128 + f];
    const float bf = b0[f];
    float s = 0.f, ss = 0.f;
    const int ntiles = (N + L0_NB - 1) / L0_NB;
    for (int t = blockIdx.x; t < ntiles; t += gridDim.x) {
        const int n0 = t * L0_NB;
        __syncthreads();
        for (int i = tid; i < L0_NB * 21; i += 256) {
            int ni = i / 21;
            int k = i - ni * 21;
            int j = k / 3;
            int c = k - j * 3;
            int n = n0 + ni;
            if (n >= N) n = N - 1;
            sX[i] = x[(long)idx[n * 7 + j] * 3 + c];
        }
        __syncthreads();
#pragma unroll
        for (int ni = 0; ni < 8; ++ni) {
            int node = n0 + half * 8 + ni;
            if (node >= N) break;   // per-thread, no barrier inside
            float acc = bf;
#pragma unroll
            for (int k = 0; k < 21; ++k)
                acc = fmaf(sX[(half * 8 + ni) * 21 + k], wreg[k], acc);
            hlin[(long)node * 128 + f] = f2h(acc);
            s += acc;
            ss += acc * acc;
        }
    }
    __syncthreads();
    if (half == 1) { sStat[f] = s; sStat[128 + f] = ss; }
    __syncthreads();
    if (half == 0) {
        atomicAdd(&stats[f], s + sStat[f]);
        atomicAdd(&stats[128 + f], ss + sStat[128 + f]);
    }
}

// ---------------------------------------------------------------------------
// gemm_mid (BN-fused, software-pipelined, FEAT-SPLIT 64 nodes x 64 feats):
//   R6 pipeline kept verbatim (fp16 gather -> fp32 BN+ReLU -> f16 sA; depth-1
//   register prefetch of A+B issued before the MFMA phase), but each block
//   computes only half the output features -> grid doubles to 1282 blocks and
//   LDS drops to ~36KB -> 4 blocks/CU resident (~16 waves/CU vs 5.3) to hide
//   the gather latency. Total B L2 traffic unchanged (each block stages its
//   own feat half); A-gather doubles but is fp16 + L3-resident.
// Block: 256 thr = 4 waves; wave = 32 nodes (wm) x 32 feats (wf); acc[2][2].
// blockIdx: tile = bx>>1 (64-node tile), fg = bx&1 (feat group of 64).
// ---------------------------------------------------------------------------
__global__ __launch_bounds__(256, 4) void gemm_mid_kernel(
        const short* __restrict__ hprev, const int* __restrict__ idx,
        const short* __restrict__ Wt, const float* __restrict__ bvec,
        const float* __restrict__ g, const float* __restrict__ be,
        const float* __restrict__ statsIn,
        short* __restrict__ hlin, float* __restrict__ statsOut,
        int N, float invN) {
    __shared__ short sA[64 * 136];   // [node][k] for current j
    __shared__ short sB[64 * 136];   // [feat_local][k] for current j
    __shared__ float sAux[256];      // sc|sh during staging; stats scratch later

    const int tid = threadIdx.x;
    const int wave = tid >> 6;
    const int lane = tid & 63;
    const int quad = lane >> 4;
    const int l16 = lane & 15;
    const int wm = wave & 1;        // node half (32 nodes)
    const int wf = wave >> 1;       // feat half of the 64 (32 feats)
    const int tile = blockIdx.x >> 1;
    const int fg = blockIdx.x & 1;  // feature group: feats [fg*64, fg*64+64)
    const int m0 = tile * 64;
    const int f0 = fg * 64;
    const int t16 = tid >> 4;       // 0..15: staging row group
    const int fb = (tid & 15) * 8;  // fixed k-chunk for staging (input feats)

    if (tid < 128) {
        float mu = statsIn[tid] * invN;
        float var = statsIn[128 + tid] * invN - mu * mu;
        float rs = rsqrtf(var + EPS);
        float sc = g[tid] * rs;
        sAux[tid] = sc;
        sAux[128 + tid] = be[tid] - mu * sc;
    }
    __syncthreads();
    float scR[8], shR[8];
#pragma unroll
    for (int e = 0; e < 8; ++e) {
        scR[e] = sAux[fb + e];
        shR[e] = sAux[128 + fb + e];
    }

    f32x4 acc[2][2];
#pragma unroll
    for (int ni = 0; ni < 2; ++ni) {
        float bv0 = bvec[f0 + wf * 32 + ni * 16 + l16];
#pragma unroll
        for (int mi = 0; mi < 2; ++mi) {
            acc[mi][ni][0] = bv0; acc[mi][ni][1] = bv0; acc[mi][ni][2] = bv0; acc[mi][ni][3] = bv0;
        }
    }

    f16x8 av[4];    // A prefetch: 4 gathered fp16 row-chunks
    f16x8 bv[4];    // B prefetch: 4 chunks of 8 fp16

    auto issueA = [&](int j) {
#pragma unroll
        for (int it = 0; it < 4; ++it) {
            int nl = t16 + it * 16;
            int n = m0 + nl;
            n = (n < N) ? n : (N - 1);
            long row = idx[n * 7 + j];
            av[it] = *(const f16x8*)&hprev[row * 128 + fb];
        }
    };
    auto issueB = [&](int j) {
#pragma unroll
        for (int it = 0; it < 4; ++it) {
            int ff = f0 + t16 + it * 16;
            bv[it] = *(const f16x8*)&Wt[(long)ff * 896 + j * 128 + fb];
        }
    };
    auto writeA = [&]() {
#pragma unroll
        for (int it = 0; it < 4; ++it) {
            int nl = t16 + it * 16;
            f16x8 hv = av[it];
            union { short sh8[8]; f16x8 v; } u;
#pragma unroll
            for (int e = 0; e < 8; ++e) {
                float v = (float)hv[e];
                u.sh8[e] = f2h(fmaxf(fmaf(v, scR[e], shR[e]), 0.f));
            }
            *(f16x8*)&sA[nl * 136 + fb] = u.v;
        }
    };
    auto writeB = [&]() {
#pragma unroll
        for (int it = 0; it < 4; ++it) {
            int ffl = t16 + it * 16;
            *(f16x8*)&sB[ffl * 136 + fb] = bv[it];
        }
    };

    issueB(0);
    issueA(0);

    for (int j = 0; j < 7; ++j) {
        __syncthreads();            // sA/sB free (previous MFMA done)
        writeB();                   // implicit vmcnt waits at first use
        writeA();
        if (j < 6) {                // issue j+1 BEFORE compute of j
            issueB(j + 1);
            issueA(j + 1);
        }
        __syncthreads();
#pragma unroll
        for (int k0 = 0; k0 < 128; k0 += 32) {
            f16x8 a[2], b[2];
#pragma unroll
            for (int mi = 0; mi < 2; ++mi)
                a[mi] = *(const f16x8*)&sA[(wm * 32 + mi * 16 + l16) * 136 + k0 + quad * 8];
#pragma unroll
            for (int ni = 0; ni < 2; ++ni)
                b[ni] = *(const f16x8*)&sB[(wf * 32 + ni * 16 + l16) * 136 + k0 + quad * 8];
#pragma unroll
            for (int mi = 0; mi < 2; ++mi)
#pragma unroll
                for (int ni = 0; ni < 2; ++ni)
                    acc[mi][ni] = __builtin_amdgcn_mfma_f32_16x16x32_f16(a[mi], b[ni], acc[mi][ni], 0, 0, 0);
        }
    }

    // epilogue: store h fp16 (pre-BN), accumulate per-feature fp32 stats
    __syncthreads();
    if (tid < 128) sAux[tid] = 0.f;
    __syncthreads();
#pragma unroll
    for (int ni = 0; ni < 2; ++ni) {
        int lf = wf * 32 + ni * 16 + l16;     // local feat 0..63
        float s = 0.f, ss = 0.f;
#pragma unroll
        for (int mi = 0; mi < 2; ++mi) {
#pragma unroll
            for (int r = 0; r < 4; ++r) {
                int node = m0 + wm * 32 + mi * 16 + quad * 4 + r;
                float v = acc[mi][ni][r];
                if (node < N) {
                    hlin[(long)node * 128 + f0 + lf] = f2h(v);
                    s += v;
                    ss += v * v;
                }
            }
        }
        atomicAdd(&sAux[lf], s);
        atomicAdd(&sAux[64 + lf], ss);
    }
    __syncthreads();
    if (tid < 64) {
        atomicAdd(&statsOut[f0 + tid], sAux[tid]);
        atomicAdd(&statsOut[128 + f0 + tid], sAux[64 + tid]);
    }
}

// ---------------------------------------------------------------------------
// gemm_final (BN-fused, software-pipelined, fp16 h gather):
//   out[N,36] = gather7(relu(bn(hprev)))[N,896] @ Wl + bl
// WtF: [48][896] fp16 (feats 36..47 zero). Block: 64 nodes, wave = 16 nodes x 48 feats.
// ---------------------------------------------------------------------------
__global__ __launch_bounds__(256) void gemm_final_kernel(
        const short* __restrict__ hprev, const int* __restrict__ idx,
        const short* __restrict__ WtF, const float* __restrict__ bl,
        const float* __restrict__ g, const float* __restrict__ be,
        const float* __restrict__ statsIn,
        float* __restrict__ out, int N, float invN) {
    __shared__ short sA[64 * 136];
    __shared__ short sB[48 * 136];
    __shared__ float sAux[256];

    const int tid = threadIdx.x;
    const int wave = tid >> 6;
    const int lane = tid & 63;
    const int quad = lane >> 4;
    const int l16 = lane & 15;
    const int m0 = blockIdx.x * 64;
    const int t16 = tid >> 4;
    const int fb = (tid & 15) * 8;

    if (tid < 128) {
        float mu = statsIn[tid] * invN;
        float var = statsIn[128 + tid] * invN - mu * mu;
        float rs = rsqrtf(var + EPS);
        float sc = g[tid] * rs;
        sAux[tid] = sc;
        sAux[128 + tid] = be[tid] - mu * sc;
    }
    __syncthreads();
    float scR[8], shR[8];
#pragma unroll
    for (int e = 0; e < 8; ++e) {
        scR[e] = sAux[fb + e];
        shR[e] = sAux[128 + fb + e];
    }

    f32x4 acc[3];
#pragma unroll
    for (int ni = 0; ni < 3; ++ni) {
        int feat = ni * 16 + l16;
        float bv0 = (feat < 36) ? bl[feat] : 0.f;
        acc[ni][0] = bv0; acc[ni][1] = bv0; acc[ni][2] = bv0; acc[ni][3] = bv0;
    }

    f16x8 av[4];
    f16x8 bv[3];

    auto issueA = [&](int j) {
#pragma unroll
        for (int it = 0; it < 4; ++it) {
            int nl = t16 + it * 16;
            int n = m0 + nl;
            n = (n < N) ? n : (N - 1);
            long row = idx[n * 7 + j];
            av[it] = *(const f16x8*)&hprev[row * 128 + fb];
        }
    };
    auto issueB = [&](int j) {
#pragma unroll
        for (int it = 0; it < 3; ++it) {
            int ff = t16 + it * 16;
            bv[it] = *(const f16x8*)&WtF[(long)ff * 896 + j * 128 + fb];
        }
    };
    auto writeA = [&]() {
#pragma unroll
        for (int it = 0; it < 4; ++it) {
            int nl = t16 + it * 16;
            f16x8 hv = av[it];
            union { short sh8[8]; f16x8 v; } u;
#pragma unroll
            for (int e = 0; e < 8; ++e) {
                float v = (float)hv[e];
                u.sh8[e] = f2h(fmaxf(fmaf(v, scR[e], shR[e]), 0.f));
            }
            *(f16x8*)&sA[nl * 136 + fb] = u.v;
        }
    };
    auto writeB = [&]() {
#pragma unroll
        for (int it = 0; it < 3; ++it) {
            int ff = t16 + it * 16;
            *(f16x8*)&sB[ff * 136 + fb] = bv[it];
        }
    };

    issueB(0);
    issueA(0);

    for (int j = 0; j < 7; ++j) {
        __syncthreads();
        writeB();
        writeA();
        if (j < 6) {
            issueB(j + 1);
            issueA(j + 1);
        }
        __syncthreads();
#pragma unroll
        for (int k0 = 0; k0 < 128; k0 += 32) {
            f16x8 a = *(const f16x8*)&sA[(wave * 16 + l16) * 136 + k0 + quad * 8];
            f16x8 b[3];
#pragma unroll
            for (int ni = 0; ni < 3; ++ni)
                b[ni] = *(const f16x8*)&sB[(ni * 16 + l16) * 136 + k0 + quad * 8];
#pragma unroll
            for (int ni = 0; ni < 3; ++ni)
                acc[ni] = __builtin_amdgcn_mfma_f32_16x16x32_f16(a, b[ni], acc[ni], 0, 0, 0);
        }
    }

#pragma unroll
    for (int ni = 0; ni < 3; ++ni) {
        int feat = ni * 16 + l16;
        if (feat < 36) {
#pragma unroll
            for (int r = 0; r < 4; ++r) {
                int node = m0 + wave * 16 + quad * 4 + r;
                if (node < N) out[(long)node * 36 + feat] = acc[ni][r];
            }
        }
    }
}

// ---------------------------------------------------------------------------
extern "C" void kernel_launch(void* const* d_in, const int* in_sizes, int n_in,
                              void* d_out, int out_size, void* d_ws, size_t ws_size,
                              hipStream_t stream) {
    const float* x   = (const float*)d_in[0];
    const int*   idx = (const int*)d_in[1];
    const float* W0  = (const float*)d_in[2];
    const float* b0  = (const float*)d_in[3];
    const float* g0  = (const float*)d_in[4];
    const float* be0 = (const float*)d_in[5];
    const float* Wm  = (const float*)d_in[6];
    const float* bm  = (const float*)d_in[7];
    const float* gm  = (const float*)d_in[8];
    const float* bem = (const float*)d_in[9];
    const float* Wl  = (const float*)d_in[10];
    const float* bl  = (const float*)d_in[11];
    float* out = (float*)d_out;

    const int N = in_sizes[0] / 3;          // 40962
    const float invN = 1.0f / (float)N;

    char* ws = (char*)d_ws;
    size_t off = 0;
    auto alloc = [&](size_t bytes) -> void* {
        void* p = ws + off;
        off = (off + bytes + 255) & ~(size_t)255;
        return p;
    };
    short* WtM   = (short*)alloc(14UL * 128 * 896 * 2);
    short* WtF   = (short*)alloc(48UL * 896 * 2);
    float* stats = (float*)alloc(15UL * 256 * 4);
    short* hlinA = (short*)alloc((size_t)N * 128 * 2);
    short* hlinB = (short*)alloc((size_t)N * 128 * 2);

    {
        long total = 14L * 896 * 128 + 48L * 896 + 15L * 256;
        int blocks = (int)((total + 255) / 256);
        prep_kernel<<<blocks, 256, 0, stream>>>(Wm, Wl, WtM, WtF, stats);
    }

    const int ntiles0 = (N + L0_NB - 1) / L0_NB;   // 2561: one tile per block
    layer0_kernel<<<ntiles0, 256, 0, stream>>>(x, idx, W0, b0, hlinA, stats, N);

    const int gblocks_mid = ((N + 63) / 64) * 2;   // 1282: (tile, feat-group)
    short* hin = hlinA;
    short* hout = hlinB;
    const float* gPrev = g0;
    const float* bePrev = be0;
    for (int L = 0; L < 14; ++L) {
        gemm_mid_kernel<<<gblocks_mid, 256, 0, stream>>>(
            hin, idx, WtM + (size_t)L * 128 * 896, bm + L * 128,
            gPrev, bePrev, stats + L * 256,
            hout, stats + (L + 1) * 256, N, invN);
        gPrev = gm + L * 128;
        bePrev = bem + L * 128;
        short* t = hin; hin = hout; hout = t;
    }

    const int gblocks_fin = (N + 63) / 64;
    gemm_final_kernel<<<gblocks_fin, 256, 0, stream>>>(
        hin, idx, WtF, bl, gm + 13 * 128, bem + 13 * 128, stats + 14 * 256,
        out, N, invN);
}

// Round 8
// 607.157 us; speedup vs baseline: 2.1357x; 1.0563x over previous
//
#include <hip/hip_runtime.h>

typedef _Float16 f16x8 __attribute__((ext_vector_type(8)));
typedef float f32x4 __attribute__((ext_vector_type(4)));

#define EPS 1e-5f

__device__ __forceinline__ short f2h(float x) {
    _Float16 h = (_Float16)x;   // round-to-nearest-even v_cvt_f16_f32
    union { _Float16 h; short s; } u;
    u.h = h;
    return u.s;
}

// ---------------------------------------------------------------------------
// prep: transpose+convert Wm -> WtM[l][f][k] fp16, Wl -> WtF[f][k] fp16 (f padded
// to 48 with zeros), zero the stats buffers. Runs every call (ws is re-poisoned).
// ---------------------------------------------------------------------------
__global__ void prep_kernel(const float* __restrict__ Wm, const float* __restrict__ Wl,
                            short* __restrict__ WtM, short* __restrict__ WtF,
                            float* __restrict__ stats) {
    const long T1 = 14L * 896 * 128;
    const long T2 = 48L * 896;
    const long T3 = 15L * 256;
    long i = (long)blockIdx.x * blockDim.x + threadIdx.x;
    if (i < T1) {
        long l = i / (896 * 128);
        long r = i % (896 * 128);
        long k = r >> 7;
        long f = r & 127;
        WtM[l * 114688 + f * 896 + k] = f2h(Wm[i]);
    } else if (i < T1 + T2) {
        long j = i - T1;
        long f = j / 896;
        long k = j % 896;
        WtF[j] = (f < 36) ? f2h(Wl[k * 36 + f]) : (short)0;
    } else if (i < T1 + T2 + T3) {
        stats[i - T1 - T2] = 0.0f;
    }
}

// ---------------------------------------------------------------------------
// layer0: h[n,f] = b0[f] + sum_{k<21} x[idx[n,k/3], k%3] * W0[k,f]
// W in 21 registers (f fixed per thread). Grid-stride (1280 blocks, ~2 tiles
// each) with depth-1 register prefetch of the gathered x staging (same
// issue-early/consume-late shape proven live in the gemm kernels): the
// idx->x dependent chain (~700cy) hides under the previous tile's compute.
// R7's one-tile-per-block variant serialized that chain per block (69.6us,
// VALUBusy 6.4%). fp32 math order unchanged; fp16 output + exact fp32 stats.
// ---------------------------------------------------------------------------
#define L0_NB 16
__global__ __launch_bounds__(256) void layer0_kernel(
        const float* __restrict__ x, const int* __restrict__ idx,
        const float* __restrict__ W0, const float* __restrict__ b0,
        short* __restrict__ hlin, float* __restrict__ stats, int N) {
    __shared__ float sX[L0_NB * 21];
    __shared__ float sStat[256];
    const int tid = threadIdx.x;
    const int f = tid & 127;
    const int half = tid >> 7;
    float wreg[21];
#pragma unroll
    for (int k = 0; k < 21; ++k) wreg[k] = W0[k * 128 + f];
    const float bf = b0[f];
    float s = 0.f, ss = 0.f;
    const int ntiles = (N + L0_NB - 1) / L0_NB;
    const int gs = gridDim.x;

    // staging element decomposition for this thread (constant across tiles)
    const int e0 = tid;                 // always < 336
    const int ni0 = e0 / 21, k0e = e0 - ni0 * 21;
    const int j0 = k0e / 3, c0 = k0e - j0 * 3;
    const int e1 = tid + 256;           // valid only for tid < 80
    const int ni1 = e1 / 21, k1e = e1 - ni1 * 21;
    const int j1 = k1e / 3, c1 = k1e - j1 * 3;

    auto issueX = [&](int t, float& a0, float& a1) {
        if (t >= ntiles) return;
        const int base = t * L0_NB;
        int n = base + ni0; if (n >= N) n = N - 1;
        a0 = x[(long)idx[n * 7 + j0] * 3 + c0];
        if (tid < 80) {
            int n2 = base + ni1; if (n2 >= N) n2 = N - 1;
            a1 = x[(long)idx[n2 * 7 + j1] * 3 + c1];
        }
    };

    float cx0 = 0.f, cx1 = 0.f, nx0 = 0.f, nx1 = 0.f;
    issueX(blockIdx.x, cx0, cx1);

    for (int t = blockIdx.x; t < ntiles; t += gs) {
        const int n0 = t * L0_NB;
        __syncthreads();                 // sX free (previous compute done)
        sX[e0] = cx0;                    // consume prefetch (vmcnt waits here)
        if (tid < 80) sX[e1] = cx1;
        issueX(t + gs, nx0, nx1);        // issue next tile BEFORE compute
        __syncthreads();
#pragma unroll
        for (int ni = 0; ni < 8; ++ni) {
            int node = n0 + half * 8 + ni;
            if (node >= N) break;        // per-thread, no barrier inside
            float acc = bf;
#pragma unroll
            for (int k = 0; k < 21; ++k)
                acc = fmaf(sX[(half * 8 + ni) * 21 + k], wreg[k], acc);
            hlin[(long)node * 128 + f] = f2h(acc);
            s += acc;
            ss += acc * acc;
        }
        cx0 = nx0; cx1 = nx1;            // plain register moves (no dyn index)
    }
    __syncthreads();
    if (half == 1) { sStat[f] = s; sStat[128 + f] = ss; }
    __syncthreads();
    if (half == 0) {
        atomicAdd(&stats[f], s + sStat[f]);
        atomicAdd(&stats[128 + f], ss + sStat[128 + f]);
    }
}

// ---------------------------------------------------------------------------
// gemm_mid (BN-fused, software-pipelined, FEAT-SPLIT 64 nodes x 64 feats):
//   fp16 gather -> fp32 BN+ReLU -> f16 sA; depth-1 register prefetch of A+B
//   issued before the MFMA phase. Each block computes half the output feats;
//   grid 1282 blocks, LDS ~36KB -> 4 blocks/CU (~16 waves/CU).
// Block: 256 thr = 4 waves; wave = 32 nodes (wm) x 32 feats (wf); acc[2][2].
// blockIdx: tile = bx>>1 (64-node tile), fg = bx&1 (feat group of 64).
// ---------------------------------------------------------------------------
__global__ __launch_bounds__(256, 4) void gemm_mid_kernel(
        const short* __restrict__ hprev, const int* __restrict__ idx,
        const short* __restrict__ Wt, const float* __restrict__ bvec,
        const float* __restrict__ g, const float* __restrict__ be,
        const float* __restrict__ statsIn,
        short* __restrict__ hlin, float* __restrict__ statsOut,
        int N, float invN) {
    __shared__ short sA[64 * 136];   // [node][k] for current j
    __shared__ short sB[64 * 136];   // [feat_local][k] for current j
    __shared__ float sAux[256];      // sc|sh during staging; stats scratch later

    const int tid = threadIdx.x;
    const int wave = tid >> 6;
    const int lane = tid & 63;
    const int quad = lane >> 4;
    const int l16 = lane & 15;
    const int wm = wave & 1;        // node half (32 nodes)
    const int wf = wave >> 1;       // feat half of the 64 (32 feats)
    const int tile = blockIdx.x >> 1;
    const int fg = blockIdx.x & 1;  // feature group: feats [fg*64, fg*64+64)
    const int m0 = tile * 64;
    const int f0 = fg * 64;
    const int t16 = tid >> 4;       // 0..15: staging row group
    const int fb = (tid & 15) * 8;  // fixed k-chunk for staging (input feats)

    if (tid < 128) {
        float mu = statsIn[tid] * invN;
        float var = statsIn[128 + tid] * invN - mu * mu;
        float rs = rsqrtf(var + EPS);
        float sc = g[tid] * rs;
        sAux[tid] = sc;
        sAux[128 + tid] = be[tid] - mu * sc;
    }
    __syncthreads();
    float scR[8], shR[8];
#pragma unroll
    for (int e = 0; e < 8; ++e) {
        scR[e] = sAux[fb + e];
        shR[e] = sAux[128 + fb + e];
    }

    f32x4 acc[2][2];
#pragma unroll
    for (int ni = 0; ni < 2; ++ni) {
        float bv0 = bvec[f0 + wf * 32 + ni * 16 + l16];
#pragma unroll
        for (int mi = 0; mi < 2; ++mi) {
            acc[mi][ni][0] = bv0; acc[mi][ni][1] = bv0; acc[mi][ni][2] = bv0; acc[mi][ni][3] = bv0;
        }
    }

    f16x8 av[4];    // A prefetch: 4 gathered fp16 row-chunks
    f16x8 bv[4];    // B prefetch: 4 chunks of 8 fp16

    auto issueA = [&](int j) {
#pragma unroll
        for (int it = 0; it < 4; ++it) {
            int nl = t16 + it * 16;
            int n = m0 + nl;
            n = (n < N) ? n : (N - 1);
            long row = idx[n * 7 + j];
            av[it] = *(const f16x8*)&hprev[row * 128 + fb];
        }
    };
    auto issueB = [&](int j) {
#pragma unroll
        for (int it = 0; it < 4; ++it) {
            int ff = f0 + t16 + it * 16;
            bv[it] = *(const f16x8*)&Wt[(long)ff * 896 + j * 128 + fb];
        }
    };
    auto writeA = [&]() {
#pragma unroll
        for (int it = 0; it < 4; ++it) {
            int nl = t16 + it * 16;
            f16x8 hv = av[it];
            union { short sh8[8]; f16x8 v; } u;
#pragma unroll
            for (int e = 0; e < 8; ++e) {
                float v = (float)hv[e];
                u.sh8[e] = f2h(fmaxf(fmaf(v, scR[e], shR[e]), 0.f));
            }
            *(f16x8*)&sA[nl * 136 + fb] = u.v;
        }
    };
    auto writeB = [&]() {
#pragma unroll
        for (int it = 0; it < 4; ++it) {
            int ffl = t16 + it * 16;
            *(f16x8*)&sB[ffl * 136 + fb] = bv[it];
        }
    };

    issueB(0);
    issueA(0);

    for (int j = 0; j < 7; ++j) {
        __syncthreads();            // sA/sB free (previous MFMA done)
        writeB();                   // implicit vmcnt waits at first use
        writeA();
        if (j < 6) {                // issue j+1 BEFORE compute of j
            issueB(j + 1);
            issueA(j + 1);
        }
        __syncthreads();
#pragma unroll
        for (int k0 = 0; k0 < 128; k0 += 32) {
            f16x8 a[2], b[2];
#pragma unroll
            for (int mi = 0; mi < 2; ++mi)
                a[mi] = *(const f16x8*)&sA[(wm * 32 + mi * 16 + l16) * 136 + k0 + quad * 8];
#pragma unroll
            for (int ni = 0; ni < 2; ++ni)
                b[ni] = *(const f16x8*)&sB[(wf * 32 + ni * 16 + l16) * 136 + k0 + quad * 8];
#pragma unroll
            for (int mi = 0; mi < 2; ++mi)
#pragma unroll
                for (int ni = 0; ni < 2; ++ni)
                    acc[mi][ni] = __builtin_amdgcn_mfma_f32_16x16x32_f16(a[mi], b[ni], acc[mi][ni], 0, 0, 0);
        }
    }

    // epilogue: store h fp16 (pre-BN), accumulate per-feature fp32 stats
    __syncthreads();
    if (tid < 128) sAux[tid] = 0.f;
    __syncthreads();
#pragma unroll
    for (int ni = 0; ni < 2; ++ni) {
        int lf = wf * 32 + ni * 16 + l16;     // local feat 0..63
        float s = 0.f, ss = 0.f;
#pragma unroll
        for (int mi = 0; mi < 2; ++mi) {
#pragma unroll
            for (int r = 0; r < 4; ++r) {
                int node = m0 + wm * 32 + mi * 16 + quad * 4 + r;
                float v = acc[mi][ni][r];
                if (node < N) {
                    hlin[(long)node * 128 + f0 + lf] = f2h(v);
                    s += v;
                    ss += v * v;
                }
            }
        }
        atomicAdd(&sAux[lf], s);
        atomicAdd(&sAux[64 + lf], ss);
    }
    __syncthreads();
    if (tid < 64) {
        atomicAdd(&statsOut[f0 + tid], sAux[tid]);
        atomicAdd(&statsOut[128 + f0 + tid], sAux[64 + tid]);
    }
}

// ---------------------------------------------------------------------------
// gemm_final (BN-fused, software-pipelined, fp16 h gather):
//   out[N,36] = gather7(relu(bn(hprev)))[N,896] @ Wl + bl
// WtF: [48][896] fp16 (feats 36..47 zero). Block: 64 nodes, wave = 16 nodes x 48 feats.
// ---------------------------------------------------------------------------
__global__ __launch_bounds__(256) void gemm_final_kernel(
        const short* __restrict__ hprev, const int* __restrict__ idx,
        const short* __restrict__ WtF, const float* __restrict__ bl,
        const float* __restrict__ g, const float* __restrict__ be,
        const float* __restrict__ statsIn,
        float* __restrict__ out, int N, float invN) {
    __shared__ short sA[64 * 136];
    __shared__ short sB[48 * 136];
    __shared__ float sAux[256];

    const int tid = threadIdx.x;
    const int wave = tid >> 6;
    const int lane = tid & 63;
    const int quad = lane >> 4;
    const int l16 = lane & 15;
    const int m0 = blockIdx.x * 64;
    const int t16 = tid >> 4;
    const int fb = (tid & 15) * 8;

    if (tid < 128) {
        float mu = statsIn[tid] * invN;
        float var = statsIn[128 + tid] * invN - mu * mu;
        float rs = rsqrtf(var + EPS);
        float sc = g[tid] * rs;
        sAux[tid] = sc;
        sAux[128 + tid] = be[tid] - mu * sc;
    }
    __syncthreads();
    float scR[8], shR[8];
#pragma unroll
    for (int e = 0; e < 8; ++e) {
        scR[e] = sAux[fb + e];
        shR[e] = sAux[128 + fb + e];
    }

    f32x4 acc[3];
#pragma unroll
    for (int ni = 0; ni < 3; ++ni) {
        int feat = ni * 16 + l16;
        float bv0 = (feat < 36) ? bl[feat] : 0.f;
        acc[ni][0] = bv0; acc[ni][1] = bv0; acc[ni][2] = bv0; acc[ni][3] = bv0;
    }

    f16x8 av[4];
    f16x8 bv[3];

    auto issueA = [&](int j) {
#pragma unroll
        for (int it = 0; it < 4; ++it) {
            int nl = t16 + it * 16;
            int n = m0 + nl;
            n = (n < N) ? n : (N - 1);
            long row = idx[n * 7 + j];
            av[it] = *(const f16x8*)&hprev[row * 128 + fb];
        }
    };
    auto issueB = [&](int j) {
#pragma unroll
        for (int it = 0; it < 3; ++it) {
            int ff = t16 + it * 16;
            bv[it] = *(const f16x8*)&WtF[(long)ff * 896 + j * 128 + fb];
        }
    };
    auto writeA = [&]() {
#pragma unroll
        for (int it = 0; it < 4; ++it) {
            int nl = t16 + it * 16;
            f16x8 hv = av[it];
            union { short sh8[8]; f16x8 v; } u;
#pragma unroll
            for (int e = 0; e < 8; ++e) {
                float v = (float)hv[e];
                u.sh8[e] = f2h(fmaxf(fmaf(v, scR[e], shR[e]), 0.f));
            }
            *(f16x8*)&sA[nl * 136 + fb] = u.v;
        }
    };
    auto writeB = [&]() {
#pragma unroll
        for (int it = 0; it < 3; ++it) {
            int ff = t16 + it * 16;
            *(f16x8*)&sB[ff * 136 + fb] = bv[it];
        }
    };

    issueB(0);
    issueA(0);

    for (int j = 0; j < 7; ++j) {
        __syncthreads();
        writeB();
        writeA();
        if (j < 6) {
            issueB(j + 1);
            issueA(j + 1);
        }
        __syncthreads();
#pragma unroll
        for (int k0 = 0; k0 < 128; k0 += 32) {
            f16x8 a = *(const f16x8*)&sA[(wave * 16 + l16) * 136 + k0 + quad * 8];
            f16x8 b[3];
#pragma unroll
            for (int ni = 0; ni < 3; ++ni)
                b[ni] = *(const f16x8*)&sB[(ni * 16 + l16) * 136 + k0 + quad * 8];
#pragma unroll
            for (int ni = 0; ni < 3; ++ni)
                acc[ni] = __builtin_amdgcn_mfma_f32_16x16x32_f16(a, b[ni], acc[ni], 0, 0, 0);
        }
    }

#pragma unroll
    for (int ni = 0; ni < 3; ++ni) {
        int feat = ni * 16 + l16;
        if (feat < 36) {
#pragma unroll
            for (int r = 0; r < 4; ++r) {
                int node = m0 + wave * 16 + quad * 4 + r;
                if (node < N) out[(long)node * 36 + feat] = acc[ni][r];
            }
        }
    }
}

// ---------------------------------------------------------------------------
extern "C" void kernel_launch(void* const* d_in, const int* in_sizes, int n_in,
                              void* d_out, int out_size, void* d_ws, size_t ws_size,
                              hipStream_t stream) {
    const float* x   = (const float*)d_in[0];
    const int*   idx = (const int*)d_in[1];
    const float* W0  = (const float*)d_in[2];
    const float* b0  = (const float*)d_in[3];
    const float* g0  = (const float*)d_in[4];
    const float* be0 = (const float*)d_in[5];
    const float* Wm  = (const float*)d_in[6];
    const float* bm  = (const float*)d_in[7];
    const float* gm  = (const float*)d_in[8];
    const float* bem = (const float*)d_in[9];
    const float* Wl  = (const float*)d_in[10];
    const float* bl  = (const float*)d_in[11];
    float* out = (float*)d_out;

    const int N = in_sizes[0] / 3;          // 40962
    const float invN = 1.0f / (float)N;

    char* ws = (char*)d_ws;
    size_t off = 0;
    auto alloc = [&](size_t bytes) -> void* {
        void* p = ws + off;
        off = (off + bytes + 255) & ~(size_t)255;
        return p;
    };
    short* WtM   = (short*)alloc(14UL * 128 * 896 * 2);
    short* WtF   = (short*)alloc(48UL * 896 * 2);
    float* stats = (float*)alloc(15UL * 256 * 4);
    short* hlinA = (short*)alloc((size_t)N * 128 * 2);
    short* hlinB = (short*)alloc((size_t)N * 128 * 2);

    {
        long total = 14L * 896 * 128 + 48L * 896 + 15L * 256;
        int blocks = (int)((total + 255) / 256);
        prep_kernel<<<blocks, 256, 0, stream>>>(Wm, Wl, WtM, WtF, stats);
    }

    layer0_kernel<<<1280, 256, 0, stream>>>(x, idx, W0, b0, hlinA, stats, N);

    const int gblocks_mid = ((N + 63) / 64) * 2;   // 1282: (tile, feat-group)
    short* hin = hlinA;
    short* hout = hlinB;
    const float* gPrev = g0;
    const float* bePrev = be0;
    for (int L = 0; L < 14; ++L) {
        gemm_mid_kernel<<<gblocks_mid, 256, 0, stream>>>(
            hin, idx, WtM + (size_t)L * 128 * 896, bm + L * 128,
            gPrev, bePrev, stats + L * 256,
            hout, stats + (L + 1) * 256, N, invN);
        gPrev = gm + L * 128;
        bePrev = bem + L * 128;
        short* t = hin; hin = hout; hout = t;
    }

    const int gblocks_fin = (N + 63) / 64;
    gemm_final_kernel<<<gblocks_fin, 256, 0, stream>>>(
        hin, idx, WtF, bl, gm + 13 * 128, bem + 13 * 128, stats + 14 * 256,
        out, N, invN);
}